// Round 18
// baseline (191.255 us; speedup 1.0000x reference)
//
#include <hip/hip_runtime.h>

// FirNeXtV2 DDSP synth. Numerics certified r13-r17 (absmax 0.0078125).
// Perf v6: all-LDS FIR inner loops — coefficient windows (zero-padded,
// uniform c0 = 512-j0) AND source windows staged in LDS; R=4/128-thread
// (lane stride = 1 bank-quad -> conflict-free b128); noise pre-scaled at
// stage time (bitwise-same value as inline scaling).

#define BLKS  512
#define WL    2048
#define W4    512
#define NB    4
#define NFR   512
#define LTOT  (NFR*BLKS)     // 262144
#define NCH   (LTOT/16)      // 16384
#define SN_LEN 260096        // WL*127

typedef float f4 __attribute__((ext_vector_type(4)));

// R=4 x 4 taps; window slides A->B. Per-output taps ascend in m.
static __device__ __forceinline__ void seg4(const float* __restrict__ P, int c0,
                                            const float* __restrict__ S,
                                            float&a0,float&a1,float&a2,float&a3) {
    f4 A = *(const f4*)(P + c0 - 4);
    #pragma unroll 8
    for (int m0 = 0; m0 < 512; m0 += 4) {
        f4 B = *(const f4*)(P + c0 + m0);
        f4 x = *(const f4*)(S + m0);
        a0 += B.x*x.x; a0 += B.y*x.y; a0 += B.z*x.z; a0 += B.w*x.w;
        a1 += A.w*x.x; a1 += B.x*x.y; a1 += B.y*x.z; a1 += B.z*x.w;
        a2 += A.z*x.x; a2 += A.w*x.y; a2 += B.x*x.z; a2 += B.y*x.w;
        a3 += A.y*x.x; a3 += A.z*x.y; a3 += A.w*x.z; a3 += B.x*x.w;
        A = B;
    }
}

// Paired harmonic+noise segment, h-tap then n-tap per element, ascending m.
static __device__ __forceinline__ void segmix(const float* __restrict__ Ph,
                                              const float* __restrict__ Pn, int c0,
                                              const float* __restrict__ Sh,
                                              const float* __restrict__ Sn,
                                              float&a0,float&a1,float&a2,float&a3) {
    f4 Ah = *(const f4*)(Ph + c0 - 4);
    f4 An = *(const f4*)(Pn + c0 - 4);
    #pragma unroll 4
    for (int m0 = 0; m0 < 512; m0 += 4) {
        f4 Bh = *(const f4*)(Ph + c0 + m0);
        f4 Bn = *(const f4*)(Pn + c0 + m0);
        f4 xh = *(const f4*)(Sh + m0);
        f4 xn = *(const f4*)(Sn + m0);
        a0 += Bh.x*xh.x; a0 += Bn.x*xn.x;  a0 += Bh.y*xh.y; a0 += Bn.y*xn.y;
        a0 += Bh.z*xh.z; a0 += Bn.z*xn.z;  a0 += Bh.w*xh.w; a0 += Bn.w*xn.w;
        a1 += Ah.w*xh.x; a1 += An.w*xn.x;  a1 += Bh.x*xh.y; a1 += Bn.x*xn.y;
        a1 += Bh.y*xh.z; a1 += Bn.y*xn.z;  a1 += Bh.z*xh.w; a1 += Bn.z*xn.w;
        a2 += Ah.z*xh.x; a2 += An.z*xn.x;  a2 += Ah.w*xh.y; a2 += An.w*xn.y;
        a2 += Bh.x*xh.z; a2 += Bn.x*xn.z;  a2 += Bh.y*xh.w; a2 += Bn.y*xn.w;
        a3 += Ah.y*xh.x; a3 += An.y*xn.x;  a3 += Ah.z*xh.y; a3 += An.z*xn.y;
        a3 += Ah.w*xh.z; a3 += An.w*xn.z;  a3 += Bh.x*xh.w; a3 += Bn.x*xn.w;
        Ah = Bh; An = Bn;
    }
}

// ---------------------------------------------------------------------------
__global__ void __launch_bounds__(256) k_scan_a(const float* __restrict__ f0_frames,
                                                float* __restrict__ L0,
                                                float* __restrict__ L1) {
    int b = blockIdx.y;
    int chunk = blockIdx.x * 256 + threadIdx.x;
    int g0 = chunk * 16;
    float d = f0_frames[b*NFR + (g0 >> 9)] / 44100.0f;
    float* o = L0 + (size_t)b*LTOT + g0;
    float acc = 0.0f;
    #pragma unroll
    for (int j = 0; j < 16; ++j) { acc = acc + d; o[j] = acc; }
    L1[(size_t)b*NCH + chunk] = acc;
}

__global__ void __launch_bounds__(1024) k_scan_b(float* __restrict__ L1g) {
    __shared__ float sL2[1024];
    __shared__ float sL3[64];
    __shared__ float sL4[4];
    int b = blockIdx.x, tid = threadIdx.x;
    float* L1 = L1g + (size_t)b*NCH;
    {
        float* p = L1 + tid*16;
        float acc = 0.0f;
        #pragma unroll
        for (int j = 0; j < 16; ++j) { acc = acc + p[j]; p[j] = acc; }
        sL2[tid] = acc;
    }
    __syncthreads();
    if (tid < 64) {
        float acc = 0.0f;
        #pragma unroll
        for (int j = 0; j < 16; ++j) { acc = acc + sL2[tid*16+j]; sL2[tid*16+j] = acc; }
        sL3[tid] = acc;
    }
    __syncthreads();
    if (tid < 4) {
        float acc = 0.0f;
        #pragma unroll
        for (int j = 0; j < 16; ++j) { acc = acc + sL3[tid*16+j]; sL3[tid*16+j] = acc; }
        sL4[tid] = acc;
    }
    __syncthreads();
    if (tid == 0) {
        float acc = 0.0f;
        #pragma unroll
        for (int j = 0; j < 4; ++j) { acc = acc + sL4[j]; sL4[j] = acc; }
    }
    __syncthreads();
    if (tid >= 16 && tid < 64) sL3[tid] = sL3[tid] + sL4[tid/16 - 1];
    __syncthreads();
    if (tid >= 16) sL2[tid] = sL2[tid] + sL3[tid/16 - 1];
    __syncthreads();
    for (int i = tid; i < NCH; i += 1024)
        if (i >= 16) L1[i] = L1[i] + sL2[i/16 - 1];
}

__global__ void __launch_bounds__(256) k_source(const float* __restrict__ f0_frames,
                                                const float* __restrict__ L0,
                                                const float* __restrict__ L1,
                                                float* __restrict__ hs) {
    int F = blockIdx.x, b = blockIdx.y;
    int tid = threadIdx.x;
    float f0 = f0_frames[b*NFR + F];
    float af = rintf(44100.0f / fmaxf(f0, 20.0f) * 0.5f) * 2.0f + 1.0f;
    const float PIF = 3.14159274101257324f;
    for (int i = tid; i < BLKS; i += 256) {
        int g = F*BLKS + i;
        float c = L0[(size_t)b*LTOT + g];
        if (g >= 16) c = c + L1[(size_t)b*NCH + (g >> 4) - 1];
        float x = c - floorf(c);
        float pix = PIF * x;
        float v;
        if (pix < 1e-8f) v = 1.0f;
        else             v = sinf(af * pix) / (af * sinf(pix));
        hs[(size_t)b*LTOT + g] = v;
    }
}

// ---------------------------------------------------------------------------
// Stage-1 FIR: 128 threads, R=4. LDS: coeff windows (16 KB) + source windows
// (8 KB, noise pre-scaled). All-LDS inner loop.
// ---------------------------------------------------------------------------
__global__ void __launch_bounds__(128) k_mix(const float* __restrict__ hs,
                                             const float* __restrict__ sn,
                                             const float* __restrict__ hks,
                                             const float* __restrict__ nk,
                                             float* __restrict__ mixg) {
    __shared__ float Wh1[1024], Wn1[1024], Wh0[1024], Wn0[1024];
    __shared__ float sH[1024], sNz[1024];
    int F = blockIdx.x, b = blockIdx.y, tid = threadIdx.x;
    const f4* khF4 = (const f4*)(hks + ((size_t)b*NFR + F)*W4);
    const f4* knF4 = (const f4*)(nk  + ((size_t)b*NFR + F)*W4);
    f4 z; z.x = z.y = z.z = z.w = 0.0f;
    for (int i = tid; i < 256; i += 128) {
        ((f4*)Wh1)[i] = (i < 128) ? khF4[i] : z;
        ((f4*)Wn1)[i] = (i < 128) ? knF4[i] : z;
        ((f4*)Wh0)[i] = (i >= 128 && F >= 1) ? khF4[i - 256] : z;  // row F-1
        ((f4*)Wn0)[i] = (i >= 128 && F >= 1) ? knF4[i - 256] : z;
    }
    int s0 = (F - 1) * BLKS;
    for (int i = tid; i < 1024; i += 128) {
        int s = s0 + i;
        float hv = 0.0f, nv = 0.0f;
        if (s >= 0) { hv = hs[(size_t)b*LTOT + s]; nv = sn[s % SN_LEN] * 0.3162f; }
        sH[i] = hv; sNz[i] = nv;
    }
    __syncthreads();
    int j0 = tid * 4;
    float a0=0,a1=0,a2=0,a3=0;
    segmix(Wh1, Wn1, 512 - j0, sH + 512, sNz + 512, a0,a1,a2,a3);   // frame F
    if (F >= 1)
        segmix(Wh0, Wn0, 512 - j0, sH, sNz, a0,a1,a2,a3);           // frame F-1
    f4 r; r.x=a0; r.y=a1; r.z=a2; r.w=a3;
    *(f4*)(mixg + (size_t)b*LTOT + (size_t)F*BLKS + j0) = r;
}

// ---------------------------------------------------------------------------
// Stage-2 FIR: 128 threads, R=4. LDS: 5 coeff windows (20 KB) + source
// window sM[2560] (10 KB). All-LDS inner loop. Segment order = r13.
// ---------------------------------------------------------------------------
__global__ void __launch_bounds__(128) k_out(const float* __restrict__ mixg,
                                             const float* __restrict__ hk,
                                             float* __restrict__ outp) {
    __shared__ float Wc[5][1024];
    __shared__ float sM[2560];
    int F = blockIdx.x, b = blockIdx.y, tid = threadIdx.x;
    f4 z; z.x = z.y = z.z = z.w = 0.0f;
    #pragma unroll
    for (int q = 0; q < 5; ++q) {
        int fs = F - 4 + q;
        const f4* row4 = (const f4*)(hk + ((size_t)b*NFR + fs)*WL);
        f4* Wp = (f4*)Wc[q];
        for (int i = tid; i < 256; i += 128) {
            f4 v = z;
            if (fs >= 0) {
                if (q == 0)      { if (i >= 128) v = row4[i - 128]; }
                else if (q == 4) { if (i < 128)  v = row4[384 + i]; }
                else             v = row4[128*(q-1) + i];
            }
            Wp[i] = v;
        }
    }
    {   // stage source window (f4 granularity; s0 is f4-aligned)
        const f4* mb4 = (const f4*)(mixg + (size_t)b*LTOT);
        int s40 = (F - 4) * (BLKS/4);
        for (int i4 = tid; i4 < 640; i4 += 128) {
            int s4 = s40 + i4;
            ((f4*)sM)[i4] = (s4 >= 0) ? mb4[s4] : z;
        }
    }
    __syncthreads();
    int j0 = tid * 4;
    float a0=0,a1=0,a2=0,a3=0;
    #pragma unroll 1
    for (int q = 1; q <= 3; ++q) {
        int fs = F - 4 + q;
        if (fs < 0) continue;                         // uniform per block
        seg4(Wc[q], 512 - j0, sM + 512*q, a0,a1,a2,a3);
    }
    seg4(Wc[4], 512 - j0, sM + 2048, a0,a1,a2,a3);
    if (F >= 4)
        seg4(Wc[0], 512 - j0, sM, a0,a1,a2,a3);
    f4 r;
    r.x = fminf(fmaxf(a0, -1.0f), 1.0f);
    r.y = fminf(fmaxf(a1, -1.0f), 1.0f);
    r.z = fminf(fmaxf(a2, -1.0f), 1.0f);
    r.w = fminf(fmaxf(a3, -1.0f), 1.0f);
    *(f4*)(outp + (size_t)b*LTOT + (size_t)F*BLKS + j0) = r;
}

// ---------------------------------------------------------------------------
extern "C" void kernel_launch(void* const* d_in, const int* in_sizes, int n_in,
                              void* d_out, int out_size, void* d_ws, size_t ws_size,
                              hipStream_t stream) {
    const float* f0  = (const float*)d_in[0];   // (B,NF,1)
    const float* hk  = (const float*)d_in[1];   // (B,NF,2048)
    const float* hks = (const float*)d_in[2];   // (B,NF,512)
    const float* nk  = (const float*)d_in[3];   // (B,NF,512)
    const float* sn  = (const float*)d_in[4];   // (260096,)
    float* outp = (float*)d_out;                // (B,L) f32

    float* ws   = (float*)d_ws;
    float* L0   = ws;                                   // NB*L     = 4 MB
    float* L1   = L0 + (size_t)NB*LTOT;                 // NB*16384 = 256 KB
    float* hsb  = L1 + (size_t)NB*NCH;                  // NB*L     = 4 MB
    float* mixg = hsb + (size_t)NB*LTOT;                // NB*L     = 4 MB

    hipLaunchKernelGGL(k_scan_a, dim3(64, NB),  dim3(256),  0, stream, f0, L0, L1);
    hipLaunchKernelGGL(k_scan_b, dim3(NB),      dim3(1024), 0, stream, L1);
    hipLaunchKernelGGL(k_source, dim3(NFR, NB), dim3(256),  0, stream, f0, L0, L1, hsb);
    hipLaunchKernelGGL(k_mix,    dim3(NFR, NB), dim3(128),  0, stream, hsb, sn, hks, nk, mixg);
    hipLaunchKernelGGL(k_out,    dim3(NFR, NB), dim3(128),  0, stream, mixg, hk, outp);
}

// Round 19
// 179.106 us; speedup vs baseline: 1.0678x; 1.0678x over previous
//
#include <hip/hip_runtime.h>

// FirNeXtV2 DDSP synth. Numerics certified r13-r18 (absmax 0.0078125).
// Perf v7 = best-of composition: r15's mixed-pipe k_out (sources + q0/q4
// coeff windows in LDS, q1-3 coeffs streamed per-lane from global/L1) +
// r17's k_mix (LDS coeff windows, wave-uniform global sources).

#define BLKS  512
#define WL    2048
#define W4    512
#define NB    4
#define NFR   512
#define LTOT  (NFR*BLKS)     // 262144
#define NCH   (LTOT/16)      // 16384
#define SN_LEN 260096        // WL*127

typedef float f4 __attribute__((ext_vector_type(4)));

// R=4 x 4 taps; window slides A->B. Per-output taps ascend in m.
static __device__ __forceinline__ void seg4(const float* __restrict__ P, int c0,
                                            const float* __restrict__ S,
                                            float&a0,float&a1,float&a2,float&a3) {
    f4 A = *(const f4*)(P + c0 - 4);
    #pragma unroll 4
    for (int m0 = 0; m0 < 512; m0 += 4) {
        f4 B = *(const f4*)(P + c0 + m0);
        f4 x = *(const f4*)(S + m0);
        a0 += B.x*x.x; a0 += B.y*x.y; a0 += B.z*x.z; a0 += B.w*x.w;
        a1 += A.w*x.x; a1 += B.x*x.y; a1 += B.y*x.z; a1 += B.z*x.w;
        a2 += A.z*x.x; a2 += A.w*x.y; a2 += B.x*x.z; a2 += B.y*x.w;
        a3 += A.y*x.x; a3 += A.z*x.y; a3 += A.w*x.z; a3 += B.x*x.w;
        A = B;
    }
}

// Paired harmonic+noise segment, h-tap then n-tap per element, ascending m.
static __device__ __forceinline__ void segmix(const float* __restrict__ Ph,
                                              const float* __restrict__ Pn, int c0,
                                              const float* __restrict__ Sh,
                                              const float* __restrict__ Sn,
                                              float&a0,float&a1,float&a2,float&a3) {
    f4 Ah = *(const f4*)(Ph + c0 - 4);
    f4 An = *(const f4*)(Pn + c0 - 4);
    #pragma unroll 4
    for (int m0 = 0; m0 < 512; m0 += 4) {
        f4 Bh = *(const f4*)(Ph + c0 + m0);
        f4 Bn = *(const f4*)(Pn + c0 + m0);
        f4 xh = *(const f4*)(Sh + m0);
        f4 xr = *(const f4*)(Sn + m0);
        f4 xn; xn.x = xr.x*0.3162f; xn.y = xr.y*0.3162f;
               xn.z = xr.z*0.3162f; xn.w = xr.w*0.3162f;
        a0 += Bh.x*xh.x; a0 += Bn.x*xn.x;  a0 += Bh.y*xh.y; a0 += Bn.y*xn.y;
        a0 += Bh.z*xh.z; a0 += Bn.z*xn.z;  a0 += Bh.w*xh.w; a0 += Bn.w*xn.w;
        a1 += Ah.w*xh.x; a1 += An.w*xn.x;  a1 += Bh.x*xh.y; a1 += Bn.x*xn.y;
        a1 += Bh.y*xh.z; a1 += Bn.y*xn.z;  a1 += Bh.z*xh.w; a1 += Bn.z*xn.w;
        a2 += Ah.z*xh.x; a2 += An.z*xn.x;  a2 += Ah.w*xh.y; a2 += An.w*xn.y;
        a2 += Bh.x*xh.z; a2 += Bn.x*xn.z;  a2 += Bh.y*xh.w; a2 += Bn.y*xn.w;
        a3 += Ah.y*xh.x; a3 += An.y*xn.x;  a3 += Ah.z*xh.y; a3 += An.z*xn.y;
        a3 += Ah.w*xh.z; a3 += An.w*xn.z;  a3 += Bh.x*xh.w; a3 += Bn.x*xn.w;
        Ah = Bh; An = Bn;
    }
}

// ---------------------------------------------------------------------------
__global__ void __launch_bounds__(256) k_scan_a(const float* __restrict__ f0_frames,
                                                float* __restrict__ L0,
                                                float* __restrict__ L1) {
    int b = blockIdx.y;
    int chunk = blockIdx.x * 256 + threadIdx.x;
    int g0 = chunk * 16;
    float d = f0_frames[b*NFR + (g0 >> 9)] / 44100.0f;
    float* o = L0 + (size_t)b*LTOT + g0;
    float acc = 0.0f;
    #pragma unroll
    for (int j = 0; j < 16; ++j) { acc = acc + d; o[j] = acc; }
    L1[(size_t)b*NCH + chunk] = acc;
}

__global__ void __launch_bounds__(1024) k_scan_b(float* __restrict__ L1g) {
    __shared__ float sL2[1024];
    __shared__ float sL3[64];
    __shared__ float sL4[4];
    int b = blockIdx.x, tid = threadIdx.x;
    float* L1 = L1g + (size_t)b*NCH;
    {
        float* p = L1 + tid*16;
        float acc = 0.0f;
        #pragma unroll
        for (int j = 0; j < 16; ++j) { acc = acc + p[j]; p[j] = acc; }
        sL2[tid] = acc;
    }
    __syncthreads();
    if (tid < 64) {
        float acc = 0.0f;
        #pragma unroll
        for (int j = 0; j < 16; ++j) { acc = acc + sL2[tid*16+j]; sL2[tid*16+j] = acc; }
        sL3[tid] = acc;
    }
    __syncthreads();
    if (tid < 4) {
        float acc = 0.0f;
        #pragma unroll
        for (int j = 0; j < 16; ++j) { acc = acc + sL3[tid*16+j]; sL3[tid*16+j] = acc; }
        sL4[tid] = acc;
    }
    __syncthreads();
    if (tid == 0) {
        float acc = 0.0f;
        #pragma unroll
        for (int j = 0; j < 4; ++j) { acc = acc + sL4[j]; sL4[j] = acc; }
    }
    __syncthreads();
    if (tid >= 16 && tid < 64) sL3[tid] = sL3[tid] + sL4[tid/16 - 1];
    __syncthreads();
    if (tid >= 16) sL2[tid] = sL2[tid] + sL3[tid/16 - 1];
    __syncthreads();
    for (int i = tid; i < NCH; i += 1024)
        if (i >= 16) L1[i] = L1[i] + sL2[i/16 - 1];
}

__global__ void __launch_bounds__(256) k_source(const float* __restrict__ f0_frames,
                                                const float* __restrict__ L0,
                                                const float* __restrict__ L1,
                                                float* __restrict__ hs) {
    int F = blockIdx.x, b = blockIdx.y;
    int tid = threadIdx.x;
    float f0 = f0_frames[b*NFR + F];
    float af = rintf(44100.0f / fmaxf(f0, 20.0f) * 0.5f) * 2.0f + 1.0f;
    const float PIF = 3.14159274101257324f;
    for (int i = tid; i < BLKS; i += 256) {
        int g = F*BLKS + i;
        float c = L0[(size_t)b*LTOT + g];
        if (g >= 16) c = c + L1[(size_t)b*NCH + (g >> 4) - 1];
        float x = c - floorf(c);
        float pix = PIF * x;
        float v;
        if (pix < 1e-8f) v = 1.0f;
        else             v = sinf(af * pix) / (af * sinf(pix));
        hs[(size_t)b*LTOT + g] = v;
    }
}

// ---------------------------------------------------------------------------
// Stage-1 FIR (r17, measured-good): 128 threads, R=4, LDS coeff windows
// (16 KB), wave-uniform global f4 source loads.
// ---------------------------------------------------------------------------
__global__ void __launch_bounds__(128) k_mix(const float* __restrict__ hs,
                                             const float* __restrict__ sn,
                                             const float* __restrict__ hks,
                                             const float* __restrict__ nk,
                                             float* __restrict__ mixg) {
    __shared__ float Wh1[1024], Wn1[1024], Wh0[1024], Wn0[1024];
    int F = blockIdx.x, b = blockIdx.y, tid = threadIdx.x;
    const f4* khF4 = (const f4*)(hks + ((size_t)b*NFR + F)*W4);
    const f4* knF4 = (const f4*)(nk  + ((size_t)b*NFR + F)*W4);
    f4 z; z.x = z.y = z.z = z.w = 0.0f;
    for (int i = tid; i < 256; i += 128) {
        ((f4*)Wh1)[i] = (i < 128) ? khF4[i] : z;
        ((f4*)Wn1)[i] = (i < 128) ? knF4[i] : z;
        ((f4*)Wh0)[i] = (i >= 128 && F >= 1) ? khF4[i - 256] : z;  // row F-1
        ((f4*)Wn0)[i] = (i >= 128 && F >= 1) ? knF4[i - 256] : z;
    }
    __syncthreads();
    int j0 = tid * 4;
    float a0=0,a1=0,a2=0,a3=0;
    const float* hsF = hs + (size_t)b*LTOT + (size_t)F*BLKS;
    segmix(Wh1, Wn1, 512 - j0, hsF, sn + (F*BLKS) % SN_LEN, a0,a1,a2,a3);
    if (F >= 1)
        segmix(Wh0, Wn0, 512 - j0, hsF - BLKS, sn + ((F-1)*BLKS) % SN_LEN,
               a0,a1,a2,a3);
    f4 r; r.x=a0; r.y=a1; r.z=a2; r.w=a3;
    *(f4*)(mixg + (size_t)b*LTOT + (size_t)F*BLKS + j0) = r;
}

// ---------------------------------------------------------------------------
// Stage-2 FIR (r15, measured-best): 128 threads, R=4. LDS: source window
// sM[2560] (broadcast reads) + zero-padded q4/q0 coeff windows (18.4 KB);
// q1-3 coefficients streamed per-lane from global (L1). Order = r13.
// ---------------------------------------------------------------------------
__global__ void __launch_bounds__(128) k_out(const float* __restrict__ mixg,
                                             const float* __restrict__ hk,
                                             float* __restrict__ outp) {
    __shared__ float sM[2560];
    __shared__ float H4[1024];     // hk row F [1536..2048), zeros above
    __shared__ float H0[1024];     // zeros below, hk row F-4 [0..512) above
    int F = blockIdx.x, b = blockIdx.y, tid = threadIdx.x;
    f4 z; z.x = z.y = z.z = z.w = 0.0f;
    {   // stage source window (f4; (F-4)*128 is f4-aligned)
        const f4* mb4 = (const f4*)(mixg + (size_t)b*LTOT);
        int s40 = (F - 4) * 128;
        for (int i4 = tid; i4 < 640; i4 += 128) {
            int s4 = s40 + i4;
            ((f4*)sM)[i4] = (s4 >= 0) ? mb4[s4] : z;
        }
    }
    const f4* rF4 = (const f4*)(hk + ((size_t)b*NFR + F)*WL);
    for (int i4 = tid; i4 < 256; i4 += 128)
        ((f4*)H4)[i4] = (i4 < 128) ? rF4[384 + i4] : z;
    {
        const f4* rA4 = (const f4*)(hk + ((size_t)b*NFR + F - 4)*WL);
        for (int i4 = tid; i4 < 256; i4 += 128) {
            f4 v = z;
            if (i4 >= 128 && F >= 4) v = rA4[i4 - 128];
            ((f4*)H0)[i4] = v;
        }
    }
    __syncthreads();
    int j0 = tid * 4;
    float a0=0,a1=0,a2=0,a3=0;
    #pragma unroll 1
    for (int q = 1; q <= 3; ++q) {
        int fs = F - 4 + q;
        if (fs < 0) continue;                         // uniform per block
        const float* P = hk + ((size_t)b*NFR + fs)*WL;
        seg4(P, 512*q - j0, sM + 512*q, a0,a1,a2,a3); // coeffs via L1
    }
    seg4(H4, 512 - j0, sM + 2048, a0,a1,a2,a3);       // row F (m<j taps)
    if (F >= 4)
        seg4(H0 + 512, -j0, sM, a0,a1,a2,a3);         // row F-4 (m>=j taps)
    f4 r;
    r.x = fminf(fmaxf(a0, -1.0f), 1.0f);
    r.y = fminf(fmaxf(a1, -1.0f), 1.0f);
    r.z = fminf(fmaxf(a2, -1.0f), 1.0f);
    r.w = fminf(fmaxf(a3, -1.0f), 1.0f);
    *(f4*)(outp + (size_t)b*LTOT + (size_t)F*BLKS + j0) = r;
}

// ---------------------------------------------------------------------------
extern "C" void kernel_launch(void* const* d_in, const int* in_sizes, int n_in,
                              void* d_out, int out_size, void* d_ws, size_t ws_size,
                              hipStream_t stream) {
    const float* f0  = (const float*)d_in[0];   // (B,NF,1)
    const float* hk  = (const float*)d_in[1];   // (B,NF,2048)
    const float* hks = (const float*)d_in[2];   // (B,NF,512)
    const float* nk  = (const float*)d_in[3];   // (B,NF,512)
    const float* sn  = (const float*)d_in[4];   // (260096,)
    float* outp = (float*)d_out;                // (B,L) f32

    float* ws   = (float*)d_ws;
    float* L0   = ws;                                   // NB*L     = 4 MB
    float* L1   = L0 + (size_t)NB*LTOT;                 // NB*16384 = 256 KB
    float* hsb  = L1 + (size_t)NB*NCH;                  // NB*L     = 4 MB
    float* mixg = hsb + (size_t)NB*LTOT;                // NB*L     = 4 MB

    hipLaunchKernelGGL(k_scan_a, dim3(64, NB),  dim3(256),  0, stream, f0, L0, L1);
    hipLaunchKernelGGL(k_scan_b, dim3(NB),      dim3(1024), 0, stream, L1);
    hipLaunchKernelGGL(k_source, dim3(NFR, NB), dim3(256),  0, stream, f0, L0, L1, hsb);
    hipLaunchKernelGGL(k_mix,    dim3(NFR, NB), dim3(128),  0, stream, hsb, sn, hks, nk, mixg);
    hipLaunchKernelGGL(k_out,    dim3(NFR, NB), dim3(128),  0, stream, mixg, hk, outp);
}